// Round 7
// baseline (932.885 us; speedup 1.0000x reference)
//
#include <hip/hip_runtime.h>

typedef _Float16 half8 __attribute__((ext_vector_type(8)));
typedef _Float16 half4 __attribute__((ext_vector_type(4)));
typedef _Float16 half2v __attribute__((ext_vector_type(2)));
typedef float floatx4 __attribute__((ext_vector_type(4)));

__device__ __forceinline__ float fast_rcp(float x) { return __builtin_amdgcn_rcpf(x); }
__device__ __forceinline__ float fast_sigmoid(float x) {
  return fast_rcp(1.f + __expf(-x));
}
__device__ __forceinline__ float fast_tanh(float x) {
  return 1.f - 2.f * fast_rcp(1.f + __expf(2.f * x));
}

// ---------------- prep: fp16 fragment-ordered weights + bias sums ----------------
// B-frag layout for mfma_f32_16x16x32_f16: lane L, reg j holds
// W[n = ntile*16 + (L&15)][k = ktile*32 + (L>>4)*8 + j].
// Buffer: [ktile][ntile(32)][lane(64)][8 f16]. Verified correct rounds 1-6.
__global__ void prep_kernel(const float* __restrict__ wih0, const float* __restrict__ whh0,
                            const float* __restrict__ bih0, const float* __restrict__ bhh0,
                            const float* __restrict__ wih1, const float* __restrict__ whh1,
                            const float* __restrict__ bih1, const float* __restrict__ bhh1,
                            _Float16* __restrict__ w0f, _Float16* __restrict__ w1f,
                            float* __restrict__ bias0, float* __restrict__ bias1)
{
  int stride = gridDim.x * blockDim.x;
  int idx0 = blockIdx.x * blockDim.x + threadIdx.x;
  const int N0 = 6*32*64*8;      // layer0: K=192 (x 64 | h 128)
  const int N1 = 8*32*64*8;      // layer1: K=256 (h1 128 | h 128)
  for (int e = idx0; e < N0 + N1 + 1024; e += stride) {
    if (e < N0) {
      int j = e & 7; int le = e >> 3; int lane = le & 63; int frag = le >> 6;
      int kt = frag >> 5, ntile = frag & 31;
      int n = ntile*16 + (lane & 15);
      int kk = kt*32 + ((lane >> 4) << 3) + j;
      float v = (kk < 64) ? wih0[n*64 + kk] : whh0[n*128 + (kk - 64)];
      w0f[e] = (_Float16)v;
    } else if (e < N0 + N1) {
      int e2 = e - N0;
      int j = e2 & 7; int le = e2 >> 3; int lane = le & 63; int frag = le >> 6;
      int kt = frag >> 5, ntile = frag & 31;
      int n = ntile*16 + (lane & 15);
      int kk = kt*32 + ((lane >> 4) << 3) + j;
      float v = (kk < 128) ? wih1[n*128 + kk] : whh1[n*128 + (kk - 128)];
      w1f[e2] = (_Float16)v;
    } else {
      int i = e - (N0 + N1);
      if (i < 512) bias0[i] = bih0[i] + bhh0[i];
      else         bias1[i - 512] = bih1[i - 512] + bhh1[i - 512];
    }
  }
}

// Compact A-frag storage: only the 8 lanes carrying rows 0,1 are stored.
// Element (r,k): frag = (k>>5)*8 + ((k&31)>>3)*2 + r, byte j = k&7.
// Reader lane L (active iff (L&15)<2) uses c = ((L>>4)<<1)|(L&1).
// Inactive lanes' A registers are zero-initialized once and NEVER written
// (exec-masked ds_read leaves dest unchanged) -> rows 2..15 stay zero.

// ---------------- layer 0: 8 waves, wave w owns gate cols [w*16,(w+1)*16) of all 4 gates ----
__global__ __launch_bounds__(512, 2) void lstm_l0(const float* __restrict__ x,
    const _Float16* __restrict__ w0f, const float* __restrict__ bias0,
    _Float16* __restrict__ h1out)
{
  const int tid = threadIdx.x;
  const int lane = tid & 63;
  const int w = tid >> 6;                 // wave 0..7
  const int r0 = blockIdx.x * 2;

  __shared__ half8 xRing[16][2*8];        // 16-step ring of compact input A-frags (4 KB)
  __shared__ half8 hA[2][4*8];            // double-buffered compact recurrent A-frags (1 KB)
  __shared__ _Float16 hist[16][2][128];   // h history ring for coalesced flush (8 KB)

  for (int i = tid; i < 2*4*8*4; i += 512) ((int*)hA)[i] = 0;

  // ntile for (gate g, wave w) = g*8 + w  ->  gate col n = g*128 + w*16 + (lane&15)
  half8 bf[6][4];                         // 24 frags = 96 AGPRs, time-invariant
#pragma unroll
  for (int kt = 0; kt < 6; ++kt)
#pragma unroll
    for (int g = 0; g < 4; ++g) {
      int frag = kt*32 + (g*8 + w);
      bf[kt][g] = *reinterpret_cast<const half8*>(w0f + (size_t)(frag*64 + lane)*8);
      asm volatile("" : "+a"(bf[kt][g]));  // pin into AGPRs
    }
  float bias_v[4];
#pragma unroll
  for (int g = 0; g < 4; ++g) bias_v[g] = bias0[g*128 + w*16 + (lane & 15)];

  // batch staging constants: thread -> (step-offset dt, row r, k-pair sk)
  const int dt = tid >> 6, su = tid & 63;
  const int sr = su >> 5, sk = (su & 31) * 2;
  const int soff = ((sk>>5)*8 + ((sk&31)>>3)*2 + sr)*8 + (sk&7);

  const bool arow = (lane & 15) < 2;       // this lane carries A rows 0/1
  const int c = ((lane >> 4) << 1) | (lane & 1);
  const int en = w*16 + (lane & 15);       // epilogue col (lanes<16)
  const int eoff = ((en>>5)*8 + ((en&31)>>3)*2)*8 + (en&7);  // r=0; r=1 at +8
  float c0 = 0.f, c1 = 0.f;

  // pre-fill ring slots 0..7 with steps 0..7
  {
    float2 v = *reinterpret_cast<const float2*>(x + ((size_t)(r0 + sr)*512 + dt)*64 + sk);
    half2v hv; hv[0] = (_Float16)v.x; hv[1] = (_Float16)v.y;
    *reinterpret_cast<half2v*>(((_Float16*)xRing[dt]) + soff) = hv;
  }
  __syncthreads();

  // loop-carried A frags; inactive lanes stay zero forever
  half8 a0 = {}, a1 = {}, a2 = {}, a3 = {}, a4 = {}, a5 = {};

  for (int t = 0; t < 512; ++t) {
    if ((t & 7) == 0) {
      // coalesced flush of steps t-8..t-1
      if (t != 0) {
        int tbase = t - 8;
        int fr = tid >> 8, rest = tid & 255;
        int fdt = rest >> 5, n = (rest & 31) * 4;
        half4 v = *reinterpret_cast<const half4*>(&hist[(tbase + fdt) & 15][fr][n]);
        *reinterpret_cast<half4*>(h1out + ((size_t)(r0 + fr)*512 + tbase + fdt)*128 + n) = v;
      }
      // batch-load x for steps t+8..t+15 into the ring (only barrier of step t drains it)
      int ts = t + 8 + dt;
      int tsc = ts < 512 ? ts : 511;
      float2 v = *reinterpret_cast<const float2*>(x + ((size_t)(r0 + sr)*512 + tsc)*64 + sk);
      half2v hv; hv[0] = (_Float16)v.x; hv[1] = (_Float16)v.y;
      *reinterpret_cast<half2v*>(((_Float16*)xRing[ts & 15]) + soff) = hv;
    }

    const int cur = t & 1;
    const int xs = t & 15;
    if (arow) {                            // 8-lane masked reads: 128 B each
      a0 = xRing[xs][0*8 + c];
      a1 = xRing[xs][1*8 + c];
      a2 = hA[cur][0*8 + c];
      a3 = hA[cur][1*8 + c];
      a4 = hA[cur][2*8 + c];
      a5 = hA[cur][3*8 + c];
    }

    floatx4 acc[4];
#pragma unroll
    for (int g = 0; g < 4; ++g) { float b = bias_v[g]; acc[g] = (floatx4){b,b,b,b}; }
#pragma unroll
    for (int g = 0; g < 4; ++g)
      acc[g] = __builtin_amdgcn_mfma_f32_16x16x32_f16(a0, bf[0][g], acc[g], 0, 0, 0);
#pragma unroll
    for (int g = 0; g < 4; ++g)
      acc[g] = __builtin_amdgcn_mfma_f32_16x16x32_f16(a1, bf[1][g], acc[g], 0, 0, 0);
#pragma unroll
    for (int g = 0; g < 4; ++g)
      acc[g] = __builtin_amdgcn_mfma_f32_16x16x32_f16(a2, bf[2][g], acc[g], 0, 0, 0);
#pragma unroll
    for (int g = 0; g < 4; ++g)
      acc[g] = __builtin_amdgcn_mfma_f32_16x16x32_f16(a3, bf[3][g], acc[g], 0, 0, 0);
#pragma unroll
    for (int g = 0; g < 4; ++g)
      acc[g] = __builtin_amdgcn_mfma_f32_16x16x32_f16(a4, bf[4][g], acc[g], 0, 0, 0);
#pragma unroll
    for (int g = 0; g < 4; ++g)
      acc[g] = __builtin_amdgcn_mfma_f32_16x16x32_f16(a5, bf[5][g], acc[g], 0, 0, 0);

    // in-register epilogue: lane<16 holds i,f,g,o for col en, rows 0..1 (C/D: col=lane&15,row=reg)
    if (lane < 16) {
      float i0 = fast_sigmoid(acc[0][0]), i1 = fast_sigmoid(acc[0][1]);
      float f0 = fast_sigmoid(acc[1][0]), f1 = fast_sigmoid(acc[1][1]);
      float g0 = fast_tanh(acc[2][0]),    g1 = fast_tanh(acc[2][1]);
      float o0 = fast_sigmoid(acc[3][0]), o1 = fast_sigmoid(acc[3][1]);
      c0 = f0*c0 + i0*g0;
      c1 = f1*c1 + i1*g1;
      float h0  = o0*fast_tanh(c0);
      float h1v = o1*fast_tanh(c1);
      _Float16 hh0 = (_Float16)h0, hh1 = (_Float16)h1v;
      const int nxt = cur ^ 1;
      ((_Float16*)hA[nxt])[eoff]     = hh0;   // r=0
      ((_Float16*)hA[nxt])[eoff + 8] = hh1;   // r=1
      hist[t & 15][0][en] = hh0;
      hist[t & 15][1][en] = hh1;
    }
    __syncthreads();                      // single barrier per step
  }
  // final flush: steps 504..511
  {
    int tbase = 504;
    int fr = tid >> 8, rest = tid & 255;
    int fdt = rest >> 5, n = (rest & 31) * 4;
    half4 v = *reinterpret_cast<const half4*>(&hist[(tbase + fdt) & 15][fr][n]);
    *reinterpret_cast<half4*>(h1out + ((size_t)(r0 + fr)*512 + tbase + fdt)*128 + n) = v;
  }
}

// ---------------- layer 1: same structure, K=256, fused linear head ----------------
__global__ __launch_bounds__(512, 2) void lstm_l1(const _Float16* __restrict__ h1in,
    const _Float16* __restrict__ w1f, const float* __restrict__ bias1,
    const float* __restrict__ wlin, const float* __restrict__ blin,
    float* __restrict__ out)
{
  const int tid = threadIdx.x;
  const int lane = tid & 63;
  const int w = tid >> 6;
  const int r0 = blockIdx.x * 2;

  __shared__ half8 iRing[16][4*8];        // 16-step ring of compact h1 A-frags (8 KB)
  __shared__ half8 hA[2][4*8];            // compact recurrent A-frags (1 KB)
  __shared__ float head[256];

  for (int i = tid; i < 2*4*8*4; i += 512) ((int*)hA)[i] = 0;

  half8 bf[8][4];                         // 32 frags = 128 AGPRs
#pragma unroll
  for (int kt = 0; kt < 8; ++kt)
#pragma unroll
    for (int g = 0; g < 4; ++g) {
      int frag = kt*32 + (g*8 + w);
      bf[kt][g] = *reinterpret_cast<const half8*>(w1f + (size_t)(frag*64 + lane)*8);
      asm volatile("" : "+a"(bf[kt][g]));
    }
  float bias_v[4];
#pragma unroll
  for (int g = 0; g < 4; ++g) bias_v[g] = bias1[g*128 + w*16 + (lane & 15)];

  // batch staging: thread -> (dt, row r, n-quad sn), fp16 passthrough as uint2
  const int dt = tid >> 6, su = tid & 63;
  const int sr = su >> 5, sn = (su & 31) * 4;
  const int soff = ((sn>>5)*8 + ((sn&31)>>3)*2 + sr)*8 + (sn&7);

  const bool arow = (lane & 15) < 2;
  const int c = ((lane >> 4) << 1) | (lane & 1);
  const int en = w*16 + (lane & 15);
  const int eoff = ((en>>5)*8 + ((en&31)>>3)*2)*8 + (en&7);
  const float wl = (lane < 16) ? wlin[en] : 0.f;
  float c0 = 0.f, c1 = 0.f;
  float hl0 = 0.f, hl1 = 0.f;

  // pre-fill ring slots 0..7
  {
    uint2 v = *reinterpret_cast<const uint2*>(h1in + ((size_t)(r0 + sr)*512 + dt)*128 + sn);
    *reinterpret_cast<uint2*>(((_Float16*)iRing[dt]) + soff) = v;
  }
  __syncthreads();

  half8 av0 = {}, av1 = {}, av2 = {}, av3 = {};   // reused for both K-halves

  for (int t = 0; t < 512; ++t) {
    if ((t & 7) == 0) {
      int ts = t + 8 + dt;
      int tsc = ts < 512 ? ts : 511;
      uint2 v = *reinterpret_cast<const uint2*>(h1in + ((size_t)(r0 + sr)*512 + tsc)*128 + sn);
      *reinterpret_cast<uint2*>(((_Float16*)iRing[ts & 15]) + soff) = v;
    }

    const int cur = t & 1;
    const int xs = t & 15;
    floatx4 acc[4];
#pragma unroll
    for (int g = 0; g < 4; ++g) { float b = bias_v[g]; acc[g] = (floatx4){b,b,b,b}; }

    if (arow) {
      av0 = iRing[xs][0*8 + c];
      av1 = iRing[xs][1*8 + c];
      av2 = iRing[xs][2*8 + c];
      av3 = iRing[xs][3*8 + c];
    }
#pragma unroll
    for (int g = 0; g < 4; ++g)
      acc[g] = __builtin_amdgcn_mfma_f32_16x16x32_f16(av0, bf[0][g], acc[g], 0, 0, 0);
#pragma unroll
    for (int g = 0; g < 4; ++g)
      acc[g] = __builtin_amdgcn_mfma_f32_16x16x32_f16(av1, bf[1][g], acc[g], 0, 0, 0);
#pragma unroll
    for (int g = 0; g < 4; ++g)
      acc[g] = __builtin_amdgcn_mfma_f32_16x16x32_f16(av2, bf[2][g], acc[g], 0, 0, 0);
#pragma unroll
    for (int g = 0; g < 4; ++g)
      acc[g] = __builtin_amdgcn_mfma_f32_16x16x32_f16(av3, bf[3][g], acc[g], 0, 0, 0);

    if (arow) {
      av0 = hA[cur][0*8 + c];
      av1 = hA[cur][1*8 + c];
      av2 = hA[cur][2*8 + c];
      av3 = hA[cur][3*8 + c];
    }
#pragma unroll
    for (int g = 0; g < 4; ++g)
      acc[g] = __builtin_amdgcn_mfma_f32_16x16x32_f16(av0, bf[4][g], acc[g], 0, 0, 0);
#pragma unroll
    for (int g = 0; g < 4; ++g)
      acc[g] = __builtin_amdgcn_mfma_f32_16x16x32_f16(av1, bf[5][g], acc[g], 0, 0, 0);
#pragma unroll
    for (int g = 0; g < 4; ++g)
      acc[g] = __builtin_amdgcn_mfma_f32_16x16x32_f16(av2, bf[6][g], acc[g], 0, 0, 0);
#pragma unroll
    for (int g = 0; g < 4; ++g)
      acc[g] = __builtin_amdgcn_mfma_f32_16x16x32_f16(av3, bf[7][g], acc[g], 0, 0, 0);

    if (lane < 16) {
      float i0 = fast_sigmoid(acc[0][0]), i1 = fast_sigmoid(acc[0][1]);
      float f0 = fast_sigmoid(acc[1][0]), f1 = fast_sigmoid(acc[1][1]);
      float g0 = fast_tanh(acc[2][0]),    g1 = fast_tanh(acc[2][1]);
      float o0 = fast_sigmoid(acc[3][0]), o1 = fast_sigmoid(acc[3][1]);
      c0 = f0*c0 + i0*g0;
      c1 = f1*c1 + i1*g1;
      hl0 = o0*fast_tanh(c0);
      hl1 = o1*fast_tanh(c1);
      const int nxt = cur ^ 1;
      ((_Float16*)hA[nxt])[eoff]     = (_Float16)hl0;
      ((_Float16*)hA[nxt])[eoff + 8] = (_Float16)hl1;
    }
    __syncthreads();
  }

  // fused head: out[r] = sum_n h_last[r][n]*wlin[n] + blin
  if (lane < 16) {
    head[en]       = hl0 * wl;
    head[128 + en] = hl1 * wl;
  }
  __syncthreads();
  if (tid < 2) {
    float s = blin[0];
    for (int n = 0; n < 128; ++n) s += head[tid*128 + n];
    out[r0 + tid] = s;
  }
}

extern "C" void kernel_launch(void* const* d_in, const int* in_sizes, int n_in,
                              void* d_out, int out_size, void* d_ws, size_t ws_size,
                              hipStream_t stream)
{
  const float* x    = (const float*)d_in[0];
  const float* wih0 = (const float*)d_in[1];
  const float* whh0 = (const float*)d_in[2];
  const float* bih0 = (const float*)d_in[3];
  const float* bhh0 = (const float*)d_in[4];
  const float* wih1 = (const float*)d_in[5];
  const float* whh1 = (const float*)d_in[6];
  const float* bih1 = (const float*)d_in[7];
  const float* bhh1 = (const float*)d_in[8];
  const float* wlin = (const float*)d_in[9];
  const float* blin = (const float*)d_in[10];
  float* out = (float*)d_out;

  char* ws = (char*)d_ws;
  _Float16* w0f = (_Float16*)(ws);               // 196608 B
  _Float16* w1f = (_Float16*)(ws + 196608);      // 262144 B
  float* bias0  = (float*)(ws + 458752);         // 2048 B
  float* bias1  = (float*)(ws + 460800);         // 2048 B
  _Float16* h1  = (_Float16*)(ws + 1048576);     // 64 MB inter-layer buffer

  prep_kernel<<<256, 256, 0, stream>>>(wih0, whh0, bih0, bhh0, wih1, whh1, bih1, bhh1,
                                       w0f, w1f, bias0, bias1);
  lstm_l0<<<256, 512, 0, stream>>>(x, w0f, bias0, h1);
  lstm_l1<<<256, 512, 0, stream>>>(h1, w1f, bias1, wlin, blin, out);
}

// Round 8
// 829.696 us; speedup vs baseline: 1.1244x; 1.1244x over previous
//
#include <hip/hip_runtime.h>

typedef _Float16 half8 __attribute__((ext_vector_type(8)));
typedef _Float16 half4 __attribute__((ext_vector_type(4)));
typedef _Float16 half2v __attribute__((ext_vector_type(2)));
typedef float floatx4 __attribute__((ext_vector_type(4)));

__device__ __forceinline__ float fast_rcp(float x) { return __builtin_amdgcn_rcpf(x); }
__device__ __forceinline__ float fast_sigmoid(float x) {
  return fast_rcp(1.f + __expf(-x));
}
__device__ __forceinline__ float fast_tanh(float x) {
  return 1.f - 2.f * fast_rcp(1.f + __expf(2.f * x));
}

// ---------------- prep: fp16 fragment-ordered weights + bias sums ----------------
// B-frag layout for mfma_f32_16x16x32_f16: lane L, reg j holds
// W[n = ntile*16 + (L&15)][k = ktile*32 + (L>>4)*8 + j].
// Buffer: [ktile][ntile(32)][lane(64)][8 f16]. Verified correct rounds 1-7.
__global__ void prep_kernel(const float* __restrict__ wih0, const float* __restrict__ whh0,
                            const float* __restrict__ bih0, const float* __restrict__ bhh0,
                            const float* __restrict__ wih1, const float* __restrict__ whh1,
                            const float* __restrict__ bih1, const float* __restrict__ bhh1,
                            _Float16* __restrict__ w0f, _Float16* __restrict__ w1f,
                            float* __restrict__ bias0, float* __restrict__ bias1)
{
  int stride = gridDim.x * blockDim.x;
  int idx0 = blockIdx.x * blockDim.x + threadIdx.x;
  const int N0 = 6*32*64*8;      // layer0: K=192 (x 64 | h 128)
  const int N1 = 8*32*64*8;      // layer1: K=256 (h1 128 | h 128)
  for (int e = idx0; e < N0 + N1 + 1024; e += stride) {
    if (e < N0) {
      int j = e & 7; int le = e >> 3; int lane = le & 63; int frag = le >> 6;
      int kt = frag >> 5, ntile = frag & 31;
      int n = ntile*16 + (lane & 15);
      int kk = kt*32 + ((lane >> 4) << 3) + j;
      float v = (kk < 64) ? wih0[n*64 + kk] : whh0[n*128 + (kk - 64)];
      w0f[e] = (_Float16)v;
    } else if (e < N0 + N1) {
      int e2 = e - N0;
      int j = e2 & 7; int le = e2 >> 3; int lane = le & 63; int frag = le >> 6;
      int kt = frag >> 5, ntile = frag & 31;
      int n = ntile*16 + (lane & 15);
      int kk = kt*32 + ((lane >> 4) << 3) + j;
      float v = (kk < 128) ? wih1[n*128 + kk] : whh1[n*128 + (kk - 128)];
      w1f[e2] = (_Float16)v;
    } else {
      int i = e - (N0 + N1);
      if (i < 512) bias0[i] = bih0[i] + bhh0[i];
      else         bias1[i - 512] = bih1[i - 512] + bhh1[i - 512];
    }
  }
}

// Compact A-frag storage, batch rows mapped to A-rows {0,4}:
//   element (r, k): frag = (k>>5)*8 + ((k&31)>>3)*2 + r,  byte j = k&7.
// Reader lane L active iff (L&15) in {0,4}  <=>  (L & 11) == 0;
//   within-group index c = ((L>>4)<<1) | ((L>>2)&1)   (k-octet, row).
// Rows 0,4 of the M=16 A-tile land in C/D REG 0, lanes 0-15 / 16-31
// -> epilogue: 32 active lanes, ONE activation chain each (was 16 lanes x 2).
// Inactive lanes' A regs zero-initialized once, never written (exec-masked
// ds_read leaves dest unchanged) -> all other A-rows stay zero.

// ---------------- layer 0: 8 waves, wave w owns gate cols [w*16,(w+1)*16) of all 4 gates ----
__global__ __launch_bounds__(512, 2) void lstm_l0(const float* __restrict__ x,
    const _Float16* __restrict__ w0f, const float* __restrict__ bias0,
    _Float16* __restrict__ h1out)
{
  const int tid = threadIdx.x;
  const int lane = tid & 63;
  const int w = tid >> 6;                 // wave 0..7
  const int r0 = blockIdx.x * 2;

  __shared__ half8 xRing[16][2*8];        // 16-step ring of compact input A-frags (4 KB)
  __shared__ half8 hA[2][4*8];            // double-buffered compact recurrent A-frags (1 KB)
  __shared__ _Float16 hist[16][2][128];   // h history ring for coalesced flush (8 KB)

  for (int i = tid; i < 2*4*8*4; i += 512) ((int*)hA)[i] = 0;

  // ntile for (gate g, wave w) = g*8 + w  ->  gate col n = g*128 + w*16 + (lane&15)
  half8 bf[6][4];                         // 24 frags = 96 AGPRs, time-invariant
#pragma unroll
  for (int kt = 0; kt < 6; ++kt)
#pragma unroll
    for (int g = 0; g < 4; ++g) {
      int frag = kt*32 + (g*8 + w);
      bf[kt][g] = *reinterpret_cast<const half8*>(w0f + (size_t)(frag*64 + lane)*8);
      asm volatile("" : "+a"(bf[kt][g]));  // pin into AGPRs
    }
  float bias_v[4];
#pragma unroll
  for (int g = 0; g < 4; ++g) bias_v[g] = bias0[g*128 + w*16 + (lane & 15)];

  // batch staging constants: thread -> (step-offset dt, row r, k-pair sk)
  const int dt = tid >> 6, su = tid & 63;
  const int sr = su >> 5, sk = (su & 31) * 2;
  const int soff = ((sk>>5)*8 + ((sk&31)>>3)*2 + sr)*8 + (sk&7);

  const bool arow = (lane & 11) == 0;                    // lane&15 in {0,4}
  const int c = ((lane >> 4) << 1) | ((lane >> 2) & 1);  // (k-octet, row)
  const int rb = lane >> 4;                // epilogue (lane<32): batch row
  const int en = w*16 + (lane & 15);       // epilogue gate col
  const int eoff = ((en>>5)*8 + ((en&31)>>3)*2 + rb)*8 + (en&7);
  float cst = 0.f;

  // pre-fill ring slots 0..7 with steps 0..7
  {
    float2 v = *reinterpret_cast<const float2*>(x + ((size_t)(r0 + sr)*512 + dt)*64 + sk);
    half2v hv; hv[0] = (_Float16)v.x; hv[1] = (_Float16)v.y;
    *reinterpret_cast<half2v*>(((_Float16*)xRing[dt]) + soff) = hv;
  }
  __syncthreads();

  // loop-carried A frags; inactive lanes stay zero forever
  half8 a0 = {}, a1 = {}, a2 = {}, a3 = {}, a4 = {}, a5 = {};

  for (int t = 0; t < 512; ++t) {
    // batch-load x for steps t+8..t+15 (WAR-safe: that slot's readers finished
    // before barrier(t-8), which this wave has passed)
    if ((t & 7) == 0) {
      int ts = t + 8 + dt;
      int tsc = ts < 512 ? ts : 511;
      float2 v = *reinterpret_cast<const float2*>(x + ((size_t)(r0 + sr)*512 + tsc)*64 + sk);
      half2v hv; hv[0] = (_Float16)v.x; hv[1] = (_Float16)v.y;
      *reinterpret_cast<half2v*>(((_Float16*)xRing[ts & 15]) + soff) = hv;
    }

    const int cur = t & 1;
    const int xs = t & 15;

    // ---- pre-barrier half: acc init + input MFMAs (ring data, ready since t-8)
    if (arow) {
      a0 = xRing[xs][0*8 + c];
      a1 = xRing[xs][1*8 + c];
    }
    floatx4 acc[4];
#pragma unroll
    for (int g = 0; g < 4; ++g) { float b = bias_v[g]; acc[g] = (floatx4){b,b,b,b}; }
#pragma unroll
    for (int g = 0; g < 4; ++g)
      acc[g] = __builtin_amdgcn_mfma_f32_16x16x32_f16(a0, bf[0][g], acc[g], 0, 0, 0);
#pragma unroll
    for (int g = 0; g < 4; ++g)
      acc[g] = __builtin_amdgcn_mfma_f32_16x16x32_f16(a1, bf[1][g], acc[g], 0, 0, 0);

    __syncthreads();                      // h(t-1) writes now visible

    // coalesced flush of steps t-8..t-1 (visible: their epilogues precede this barrier)
    if ((t & 7) == 0 && t != 0) {
      int tbase = t - 8;
      int fr = tid >> 8, rest = tid & 255;
      int fdt = rest >> 5, n = (rest & 31) * 4;
      half4 v = *reinterpret_cast<const half4*>(&hist[(tbase + fdt) & 15][fr][n]);
      *reinterpret_cast<half4*>(h1out + ((size_t)(r0 + fr)*512 + tbase + fdt)*128 + n) = v;
    }

    // ---- post-barrier half: recurrent MFMAs
    if (arow) {
      a2 = hA[cur][0*8 + c];
      a3 = hA[cur][1*8 + c];
      a4 = hA[cur][2*8 + c];
      a5 = hA[cur][3*8 + c];
    }
#pragma unroll
    for (int g = 0; g < 4; ++g)
      acc[g] = __builtin_amdgcn_mfma_f32_16x16x32_f16(a2, bf[2][g], acc[g], 0, 0, 0);
#pragma unroll
    for (int g = 0; g < 4; ++g)
      acc[g] = __builtin_amdgcn_mfma_f32_16x16x32_f16(a3, bf[3][g], acc[g], 0, 0, 0);
#pragma unroll
    for (int g = 0; g < 4; ++g)
      acc[g] = __builtin_amdgcn_mfma_f32_16x16x32_f16(a4, bf[4][g], acc[g], 0, 0, 0);
#pragma unroll
    for (int g = 0; g < 4; ++g)
      acc[g] = __builtin_amdgcn_mfma_f32_16x16x32_f16(a5, bf[5][g], acc[g], 0, 0, 0);

    // epilogue: 32 active lanes, one (row,col) each; rows 0,4 of C/D are reg 0
    if (lane < 32) {
      float ii = fast_sigmoid(acc[0][0]);
      float ff = fast_sigmoid(acc[1][0]);
      float gg = fast_tanh(acc[2][0]);
      float oo = fast_sigmoid(acc[3][0]);
      cst = ff*cst + ii*gg;
      float hv = oo*fast_tanh(cst);
      _Float16 hh = (_Float16)hv;
      const int nxt = cur ^ 1;
      ((_Float16*)hA[nxt])[eoff] = hh;
      hist[t & 15][rb][en] = hh;
    }
    // next iteration's barrier orders these writes vs readers
  }
  // final flush: steps 504..511 (need a barrier to see other waves' last epilogues)
  __syncthreads();
  {
    int tbase = 504;
    int fr = tid >> 8, rest = tid & 255;
    int fdt = rest >> 5, n = (rest & 31) * 4;
    half4 v = *reinterpret_cast<const half4*>(&hist[(tbase + fdt) & 15][fr][n]);
    *reinterpret_cast<half4*>(h1out + ((size_t)(r0 + fr)*512 + tbase + fdt)*128 + n) = v;
  }
}

// ---------------- layer 1: same structure, K=256, fused linear head ----------------
__global__ __launch_bounds__(512, 2) void lstm_l1(const _Float16* __restrict__ h1in,
    const _Float16* __restrict__ w1f, const float* __restrict__ bias1,
    const float* __restrict__ wlin, const float* __restrict__ blin,
    float* __restrict__ out)
{
  const int tid = threadIdx.x;
  const int lane = tid & 63;
  const int w = tid >> 6;
  const int r0 = blockIdx.x * 2;

  __shared__ half8 iRing[16][4*8];        // 16-step ring of compact h1 A-frags (8 KB)
  __shared__ half8 hA[2][4*8];            // compact recurrent A-frags (1 KB)
  __shared__ float head[256];

  for (int i = tid; i < 2*4*8*4; i += 512) ((int*)hA)[i] = 0;

  half8 bf[8][4];                         // 32 frags = 128 AGPRs
#pragma unroll
  for (int kt = 0; kt < 8; ++kt)
#pragma unroll
    for (int g = 0; g < 4; ++g) {
      int frag = kt*32 + (g*8 + w);
      bf[kt][g] = *reinterpret_cast<const half8*>(w1f + (size_t)(frag*64 + lane)*8);
      asm volatile("" : "+a"(bf[kt][g]));
    }
  float bias_v[4];
#pragma unroll
  for (int g = 0; g < 4; ++g) bias_v[g] = bias1[g*128 + w*16 + (lane & 15)];

  // batch staging: thread -> (dt, row r, n-quad sn), fp16 passthrough as uint2
  const int dt = tid >> 6, su = tid & 63;
  const int sr = su >> 5, sn = (su & 31) * 4;
  const int soff = ((sn>>5)*8 + ((sn&31)>>3)*2 + sr)*8 + (sn&7);

  const bool arow = (lane & 11) == 0;
  const int c = ((lane >> 4) << 1) | ((lane >> 2) & 1);
  const int rb = lane >> 4;
  const int en = w*16 + (lane & 15);
  const int eoff = ((en>>5)*8 + ((en&31)>>3)*2 + rb)*8 + (en&7);
  const float wl = (lane < 32) ? wlin[en] : 0.f;
  float cst = 0.f;
  float hl = 0.f;

  // pre-fill ring slots 0..7
  {
    uint2 v = *reinterpret_cast<const uint2*>(h1in + ((size_t)(r0 + sr)*512 + dt)*128 + sn);
    *reinterpret_cast<uint2*>(((_Float16*)iRing[dt]) + soff) = v;
  }
  __syncthreads();

  half8 ai0 = {}, ai1 = {}, ai2 = {}, ai3 = {};
  half8 ah0 = {}, ah1 = {}, ah2 = {}, ah3 = {};

  for (int t = 0; t < 512; ++t) {
    if ((t & 7) == 0) {
      int ts = t + 8 + dt;
      int tsc = ts < 512 ? ts : 511;
      uint2 v = *reinterpret_cast<const uint2*>(h1in + ((size_t)(r0 + sr)*512 + tsc)*128 + sn);
      *reinterpret_cast<uint2*>(((_Float16*)iRing[ts & 15]) + soff) = v;
    }

    const int cur = t & 1;
    const int xs = t & 15;

    // ---- pre-barrier half: input MFMAs (K=128 from h1 ring)
    if (arow) {
      ai0 = iRing[xs][0*8 + c];
      ai1 = iRing[xs][1*8 + c];
      ai2 = iRing[xs][2*8 + c];
      ai3 = iRing[xs][3*8 + c];
    }
    floatx4 acc[4];
#pragma unroll
    for (int g = 0; g < 4; ++g) { float b = bias_v[g]; acc[g] = (floatx4){b,b,b,b}; }
#pragma unroll
    for (int g = 0; g < 4; ++g)
      acc[g] = __builtin_amdgcn_mfma_f32_16x16x32_f16(ai0, bf[0][g], acc[g], 0, 0, 0);
#pragma unroll
    for (int g = 0; g < 4; ++g)
      acc[g] = __builtin_amdgcn_mfma_f32_16x16x32_f16(ai1, bf[1][g], acc[g], 0, 0, 0);
#pragma unroll
    for (int g = 0; g < 4; ++g)
      acc[g] = __builtin_amdgcn_mfma_f32_16x16x32_f16(ai2, bf[2][g], acc[g], 0, 0, 0);
#pragma unroll
    for (int g = 0; g < 4; ++g)
      acc[g] = __builtin_amdgcn_mfma_f32_16x16x32_f16(ai3, bf[3][g], acc[g], 0, 0, 0);

    __syncthreads();                      // h2(t-1) visible

    // ---- post-barrier half: recurrent MFMAs
    if (arow) {
      ah0 = hA[cur][0*8 + c];
      ah1 = hA[cur][1*8 + c];
      ah2 = hA[cur][2*8 + c];
      ah3 = hA[cur][3*8 + c];
    }
#pragma unroll
    for (int g = 0; g < 4; ++g)
      acc[g] = __builtin_amdgcn_mfma_f32_16x16x32_f16(ah0, bf[4][g], acc[g], 0, 0, 0);
#pragma unroll
    for (int g = 0; g < 4; ++g)
      acc[g] = __builtin_amdgcn_mfma_f32_16x16x32_f16(ah1, bf[5][g], acc[g], 0, 0, 0);
#pragma unroll
    for (int g = 0; g < 4; ++g)
      acc[g] = __builtin_amdgcn_mfma_f32_16x16x32_f16(ah2, bf[6][g], acc[g], 0, 0, 0);
#pragma unroll
    for (int g = 0; g < 4; ++g)
      acc[g] = __builtin_amdgcn_mfma_f32_16x16x32_f16(ah3, bf[7][g], acc[g], 0, 0, 0);

    if (lane < 32) {
      float ii = fast_sigmoid(acc[0][0]);
      float ff = fast_sigmoid(acc[1][0]);
      float gg = fast_tanh(acc[2][0]);
      float oo = fast_sigmoid(acc[3][0]);
      cst = ff*cst + ii*gg;
      hl = oo*fast_tanh(cst);
      const int nxt = cur ^ 1;
      ((_Float16*)hA[nxt])[eoff] = (_Float16)hl;
    }
  }

  // fused head: out[r] = sum_n h_last[r][n]*wlin[n] + blin
  if (lane < 32) head[rb*128 + en] = hl * wl;
  __syncthreads();
  if (tid < 2) {
    float s = blin[0];
    for (int n = 0; n < 128; ++n) s += head[tid*128 + n];
    out[r0 + tid] = s;
  }
}

extern "C" void kernel_launch(void* const* d_in, const int* in_sizes, int n_in,
                              void* d_out, int out_size, void* d_ws, size_t ws_size,
                              hipStream_t stream)
{
  const float* x    = (const float*)d_in[0];
  const float* wih0 = (const float*)d_in[1];
  const float* whh0 = (const float*)d_in[2];
  const float* bih0 = (const float*)d_in[3];
  const float* bhh0 = (const float*)d_in[4];
  const float* wih1 = (const float*)d_in[5];
  const float* whh1 = (const float*)d_in[6];
  const float* bih1 = (const float*)d_in[7];
  const float* bhh1 = (const float*)d_in[8];
  const float* wlin = (const float*)d_in[9];
  const float* blin = (const float*)d_in[10];
  float* out = (float*)d_out;

  char* ws = (char*)d_ws;
  _Float16* w0f = (_Float16*)(ws);               // 196608 B
  _Float16* w1f = (_Float16*)(ws + 196608);      // 262144 B
  float* bias0  = (float*)(ws + 458752);         // 2048 B
  float* bias1  = (float*)(ws + 460800);         // 2048 B
  _Float16* h1  = (_Float16*)(ws + 1048576);     // 64 MB inter-layer buffer

  prep_kernel<<<256, 256, 0, stream>>>(wih0, whh0, bih0, bhh0, wih1, whh1, bih1, bhh1,
                                       w0f, w1f, bias0, bias1);
  lstm_l0<<<256, 512, 0, stream>>>(x, w0f, bias0, h1);
  lstm_l1<<<256, 512, 0, stream>>>(h1, w1f, bias1, wlin, blin, out);
}

// Round 9
// 782.386 us; speedup vs baseline: 1.1924x; 1.0605x over previous
//
#include <hip/hip_runtime.h>

typedef _Float16 half8 __attribute__((ext_vector_type(8)));
typedef _Float16 half4 __attribute__((ext_vector_type(4)));
typedef _Float16 half2v __attribute__((ext_vector_type(2)));
typedef float floatx4 __attribute__((ext_vector_type(4)));

__device__ __forceinline__ float fast_rcp(float x) { return __builtin_amdgcn_rcpf(x); }
__device__ __forceinline__ float fast_sigmoid(float x) {
  return fast_rcp(1.f + __expf(-x));
}
__device__ __forceinline__ float fast_tanh(float x) {
  return 1.f - 2.f * fast_rcp(1.f + __expf(2.f * x));
}

// ---------------- prep: fp16 fragment-ordered weights + bias sums ----------------
// B-frag layout for mfma_f32_16x16x32_f16: lane L, reg j holds
// W[n = ntile*16 + (L&15)][k = ktile*32 + (L>>4)*8 + j].
// Buffer: [ktile][ntile(32)][lane(64)][8 f16]. Verified correct rounds 1-8.
__global__ void prep_kernel(const float* __restrict__ wih0, const float* __restrict__ whh0,
                            const float* __restrict__ bih0, const float* __restrict__ bhh0,
                            const float* __restrict__ wih1, const float* __restrict__ whh1,
                            const float* __restrict__ bih1, const float* __restrict__ bhh1,
                            _Float16* __restrict__ w0f, _Float16* __restrict__ w1f,
                            float* __restrict__ bias0, float* __restrict__ bias1)
{
  int stride = gridDim.x * blockDim.x;
  int idx0 = blockIdx.x * blockDim.x + threadIdx.x;
  const int N0 = 6*32*64*8;      // layer0: K=192 (x 64 | h 128)
  const int N1 = 8*32*64*8;      // layer1: K=256 (h1 128 | h 128)
  for (int e = idx0; e < N0 + N1 + 1024; e += stride) {
    if (e < N0) {
      int j = e & 7; int le = e >> 3; int lane = le & 63; int frag = le >> 6;
      int kt = frag >> 5, ntile = frag & 31;
      int n = ntile*16 + (lane & 15);
      int kk = kt*32 + ((lane >> 4) << 3) + j;
      float v = (kk < 64) ? wih0[n*64 + kk] : whh0[n*128 + (kk - 64)];
      w0f[e] = (_Float16)v;
    } else if (e < N0 + N1) {
      int e2 = e - N0;
      int j = e2 & 7; int le = e2 >> 3; int lane = le & 63; int frag = le >> 6;
      int kt = frag >> 5, ntile = frag & 31;
      int n = ntile*16 + (lane & 15);
      int kk = kt*32 + ((lane >> 4) << 3) + j;
      float v = (kk < 128) ? wih1[n*128 + kk] : whh1[n*128 + (kk - 128)];
      w1f[e2] = (_Float16)v;
    } else {
      int i = e - (N0 + N1);
      if (i < 512) bias0[i] = bih0[i] + bhh0[i];
      else         bias1[i - 512] = bih1[i - 512] + bhh1[i - 512];
    }
  }
}

// Batched input projection: pack (8 steps x 2 rows) = 16 full M-rows, m = dt*2 + r.
// Full A-frag layout: lane L holds A[m=L&15][k=kt*32+(L>>4)*8+j];
//   half index (kt*64 + (m + ((k&31)>>3)*16))*8 + (k&7).
// Pre-activations (bias folded) stored fp32: preLDS[buf][(m*128 + en)*4 + g].
// Pipeline at batch b (t=8b): stage batch b+2 -> aF[b&1] (pre-barrier);
//   MFMA aF[(b+1)&1] -> preLDS[(b+1)&1] (post-barrier); steps read preLDS[b&1].
// Recurrent half unchanged from r8: compact rows {0,4}, lane active iff (L&11)==0,
//   epilogue on 32 lanes via C/D reg 0.

// ---------------- layer 0 ----------------
__global__ __launch_bounds__(512, 2) void lstm_l0(const float* __restrict__ x,
    const _Float16* __restrict__ w0f, const float* __restrict__ bias0,
    _Float16* __restrict__ h1out)
{
  const int tid = threadIdx.x;
  const int lane = tid & 63;
  const int w = tid >> 6;
  const int r0 = blockIdx.x * 2;

  __shared__ float preLDS[2][8192];       // 2 x 32 KB pre-activation buffers
  __shared__ half8 aF[2][2*64];           // input A-frags, 2 ktiles (K=64), 2 x 2 KB
  __shared__ half8 hA[2][4*8];            // compact recurrent frags (1 KB)
  __shared__ _Float16 hist[16][2][128];   // h history ring (8 KB)

  for (int i = tid; i < 2*4*8*4; i += 512) ((int*)hA)[i] = 0;

  half8 bf[6][4];                         // 24 frags = 96 AGPRs
#pragma unroll
  for (int kt = 0; kt < 6; ++kt)
#pragma unroll
    for (int g = 0; g < 4; ++g) {
      int frag = kt*32 + (g*8 + w);
      bf[kt][g] = *reinterpret_cast<const half8*>(w0f + (size_t)(frag*64 + lane)*8);
      asm volatile("" : "+a"(bf[kt][g]));
    }
  float bias_v[4];
#pragma unroll
  for (int g = 0; g < 4; ++g) bias_v[g] = bias0[g*128 + w*16 + (lane & 15)];

  // staging: thread -> (dt, r, col-pair); full A-frag half index
  const int sdt = tid >> 6, sr = (tid >> 5) & 1, scp = (tid & 31) * 2;
  const int sm = sdt*2 + sr;
  const int sidx = ((scp>>5)*64 + sm + (((scp&31)>>3)<<4))*8 + (scp & 7);

  const bool arow = (lane & 11) == 0;
  const int cIdx = ((lane >> 4) << 1) | ((lane >> 2) & 1);
  const int rb = lane >> 4;
  const int en = w*16 + (lane & 15);
  const int eoff = ((en>>5)*8 + ((en&31)>>3)*2 + rb)*8 + (en&7);
  float cst = 0.f;

  // prologue: stage batches 0 and 1
  {
    float2 v0 = *reinterpret_cast<const float2*>(x + ((size_t)(r0+sr)*512 + sdt)*64 + scp);
    float2 v1 = *reinterpret_cast<const float2*>(x + ((size_t)(r0+sr)*512 + 8 + sdt)*64 + scp);
    half2v h0; h0[0] = (_Float16)v0.x; h0[1] = (_Float16)v0.y;
    half2v h1v; h1v[0] = (_Float16)v1.x; h1v[1] = (_Float16)v1.y;
    *reinterpret_cast<half2v*>(((_Float16*)aF[0]) + sidx) = h0;
    *reinterpret_cast<half2v*>(((_Float16*)aF[1]) + sidx) = h1v;
  }
  __syncthreads();
  {                                        // pre[batch0] -> preLDS[0]
    floatx4 accP[4];
#pragma unroll
    for (int g = 0; g < 4; ++g) { float bb = bias_v[g]; accP[g] = (floatx4){bb,bb,bb,bb}; }
#pragma unroll
    for (int kt = 0; kt < 2; ++kt) {
      half8 af = aF[0][kt*64 + lane];
#pragma unroll
      for (int g = 0; g < 4; ++g)
        accP[g] = __builtin_amdgcn_mfma_f32_16x16x32_f16(af, bf[kt][g], accP[g], 0, 0, 0);
    }
#pragma unroll
    for (int reg = 0; reg < 4; ++reg) {
      int m = ((lane>>4)<<2) + reg;
      floatx4 pv = (floatx4){accP[0][reg], accP[1][reg], accP[2][reg], accP[3][reg]};
      *reinterpret_cast<floatx4*>(&preLDS[0][(m*128 + en)*4]) = pv;
    }
  }
  __syncthreads();

  half8 a2 = {}, a3 = {}, a4 = {}, a5 = {};

  for (int t = 0; t < 512; ++t) {
    const int b = t >> 3;
    if ((t & 7) == 0 && b < 62) {          // stage batch b+2 -> aF[b&1]
      int s = (b+2)*8 + sdt;
      float2 v = *reinterpret_cast<const float2*>(x + ((size_t)(r0+sr)*512 + s)*64 + scp);
      half2v hv; hv[0] = (_Float16)v.x; hv[1] = (_Float16)v.y;
      *reinterpret_cast<half2v*>(((_Float16*)aF[b&1]) + sidx) = hv;
    }
    __syncthreads();
    if ((t & 7) == 0) {
      if (t != 0) {                        // coalesced flush of steps t-8..t-1
        int tbase = t - 8;
        int fr = tid >> 8, rest = tid & 255;
        int fdt = rest >> 5, n = (rest & 31) * 4;
        half4 v = *reinterpret_cast<const half4*>(&hist[(tbase + fdt) & 15][fr][n]);
        *reinterpret_cast<half4*>(h1out + ((size_t)(r0 + fr)*512 + tbase + fdt)*128 + n) = v;
      }
      if (b < 63) {                        // pre[batch b+1] -> preLDS[(b+1)&1]
        int slot = (b+1) & 1;
        floatx4 accP[4];
#pragma unroll
        for (int g = 0; g < 4; ++g) { float bb = bias_v[g]; accP[g] = (floatx4){bb,bb,bb,bb}; }
#pragma unroll
        for (int kt = 0; kt < 2; ++kt) {
          half8 af = aF[slot][kt*64 + lane];
#pragma unroll
          for (int g = 0; g < 4; ++g)
            accP[g] = __builtin_amdgcn_mfma_f32_16x16x32_f16(af, bf[kt][g], accP[g], 0, 0, 0);
        }
#pragma unroll
        for (int reg = 0; reg < 4; ++reg) {
          int m = ((lane>>4)<<2) + reg;
          floatx4 pv = (floatx4){accP[0][reg], accP[1][reg], accP[2][reg], accP[3][reg]};
          *reinterpret_cast<floatx4*>(&preLDS[slot][(m*128 + en)*4]) = pv;
        }
      }
    }

    // acc init from precomputed input projection (one masked 16B LDS read)
    floatx4 p4 = (floatx4){0.f, 0.f, 0.f, 0.f};
    if (lane < 32) {
      int mstep = ((t & 7) << 1) + rb;
      p4 = *reinterpret_cast<const floatx4*>(&preLDS[b & 1][(mstep*128 + en)*4]);
    }
    floatx4 acc[4];
#pragma unroll
    for (int g = 0; g < 4; ++g) acc[g] = (floatx4){p4[g], 0.f, 0.f, 0.f};

    const int cur = t & 1;
    if (arow) {
      a2 = hA[cur][0*8 + cIdx];
      a3 = hA[cur][1*8 + cIdx];
      a4 = hA[cur][2*8 + cIdx];
      a5 = hA[cur][3*8 + cIdx];
    }
#pragma unroll
    for (int g = 0; g < 4; ++g)
      acc[g] = __builtin_amdgcn_mfma_f32_16x16x32_f16(a2, bf[2][g], acc[g], 0, 0, 0);
#pragma unroll
    for (int g = 0; g < 4; ++g)
      acc[g] = __builtin_amdgcn_mfma_f32_16x16x32_f16(a3, bf[3][g], acc[g], 0, 0, 0);
#pragma unroll
    for (int g = 0; g < 4; ++g)
      acc[g] = __builtin_amdgcn_mfma_f32_16x16x32_f16(a4, bf[4][g], acc[g], 0, 0, 0);
#pragma unroll
    for (int g = 0; g < 4; ++g)
      acc[g] = __builtin_amdgcn_mfma_f32_16x16x32_f16(a5, bf[5][g], acc[g], 0, 0, 0);

    if (lane < 32) {
      float ii = fast_sigmoid(acc[0][0]);
      float ff = fast_sigmoid(acc[1][0]);
      float gg = fast_tanh(acc[2][0]);
      float oo = fast_sigmoid(acc[3][0]);
      cst = ff*cst + ii*gg;
      float hv2 = oo*fast_tanh(cst);
      _Float16 hh = (_Float16)hv2;
      ((_Float16*)hA[cur^1])[eoff] = hh;
      hist[t & 15][rb][en] = hh;
    }
  }
  __syncthreads();
  {                                        // final flush: steps 504..511
    int tbase = 504;
    int fr = tid >> 8, rest = tid & 255;
    int fdt = rest >> 5, n = (rest & 31) * 4;
    half4 v = *reinterpret_cast<const half4*>(&hist[(tbase + fdt) & 15][fr][n]);
    *reinterpret_cast<half4*>(h1out + ((size_t)(r0 + fr)*512 + tbase + fdt)*128 + n) = v;
  }
}

// ---------------- layer 1: K_in = 128 (4 ktiles), fused linear head ----------------
__global__ __launch_bounds__(512, 2) void lstm_l1(const _Float16* __restrict__ h1in,
    const _Float16* __restrict__ w1f, const float* __restrict__ bias1,
    const float* __restrict__ wlin, const float* __restrict__ blin,
    float* __restrict__ out)
{
  const int tid = threadIdx.x;
  const int lane = tid & 63;
  const int w = tid >> 6;
  const int r0 = blockIdx.x * 2;

  __shared__ float preLDS[2][8192];       // 2 x 32 KB
  __shared__ half8 aF[2][4*64];           // input A-frags, 4 ktiles (K=128), 2 x 4 KB
  __shared__ half8 hA[2][4*8];
  __shared__ float head[256];

  for (int i = tid; i < 2*4*8*4; i += 512) ((int*)hA)[i] = 0;

  half8 bf[8][4];                         // 32 frags = 128 AGPRs
#pragma unroll
  for (int kt = 0; kt < 8; ++kt)
#pragma unroll
    for (int g = 0; g < 4; ++g) {
      int frag = kt*32 + (g*8 + w);
      bf[kt][g] = *reinterpret_cast<const half8*>(w1f + (size_t)(frag*64 + lane)*8);
      asm volatile("" : "+a"(bf[kt][g]));
    }
  float bias_v[4];
#pragma unroll
  for (int g = 0; g < 4; ++g) bias_v[g] = bias1[g*128 + w*16 + (lane & 15)];

  // staging: thread -> (dt, r, col-quad); fp16 passthrough (8B)
  const int sdt = tid >> 6, sr = (tid >> 5) & 1, scq = (tid & 31) * 4;
  const int sm = sdt*2 + sr;
  const int sidx = ((scq>>5)*64 + sm + (((scq&31)>>3)<<4))*8 + (scq & 7);

  const bool arow = (lane & 11) == 0;
  const int cIdx = ((lane >> 4) << 1) | ((lane >> 2) & 1);
  const int rb = lane >> 4;
  const int en = w*16 + (lane & 15);
  const int eoff = ((en>>5)*8 + ((en&31)>>3)*2 + rb)*8 + (en&7);
  const float wl = (lane < 32) ? wlin[en] : 0.f;
  float cst = 0.f;
  float hl = 0.f;

  // prologue: stage batches 0 and 1
  {
    uint2 v0 = *reinterpret_cast<const uint2*>(h1in + ((size_t)(r0+sr)*512 + sdt)*128 + scq);
    uint2 v1 = *reinterpret_cast<const uint2*>(h1in + ((size_t)(r0+sr)*512 + 8 + sdt)*128 + scq);
    *reinterpret_cast<uint2*>(((_Float16*)aF[0]) + sidx) = v0;
    *reinterpret_cast<uint2*>(((_Float16*)aF[1]) + sidx) = v1;
  }
  __syncthreads();
  {                                        // pre[batch0] -> preLDS[0]
    floatx4 accP[4];
#pragma unroll
    for (int g = 0; g < 4; ++g) { float bb = bias_v[g]; accP[g] = (floatx4){bb,bb,bb,bb}; }
#pragma unroll
    for (int kt = 0; kt < 4; ++kt) {
      half8 af = aF[0][kt*64 + lane];
#pragma unroll
      for (int g = 0; g < 4; ++g)
        accP[g] = __builtin_amdgcn_mfma_f32_16x16x32_f16(af, bf[kt][g], accP[g], 0, 0, 0);
    }
#pragma unroll
    for (int reg = 0; reg < 4; ++reg) {
      int m = ((lane>>4)<<2) + reg;
      floatx4 pv = (floatx4){accP[0][reg], accP[1][reg], accP[2][reg], accP[3][reg]};
      *reinterpret_cast<floatx4*>(&preLDS[0][(m*128 + en)*4]) = pv;
    }
  }
  __syncthreads();

  half8 a4 = {}, a5 = {}, a6 = {}, a7 = {};

  for (int t = 0; t < 512; ++t) {
    const int b = t >> 3;
    if ((t & 7) == 0 && b < 62) {          // stage batch b+2 -> aF[b&1]
      int s = (b+2)*8 + sdt;
      uint2 v = *reinterpret_cast<const uint2*>(h1in + ((size_t)(r0+sr)*512 + s)*128 + scq);
      *reinterpret_cast<uint2*>(((_Float16*)aF[b&1]) + sidx) = v;
    }
    __syncthreads();
    if ((t & 7) == 0 && b < 63) {          // pre[batch b+1] -> preLDS[(b+1)&1]
      int slot = (b+1) & 1;
      floatx4 accP[4];
#pragma unroll
      for (int g = 0; g < 4; ++g) { float bb = bias_v[g]; accP[g] = (floatx4){bb,bb,bb,bb}; }
#pragma unroll
      for (int kt = 0; kt < 4; ++kt) {
        half8 af = aF[slot][kt*64 + lane];
#pragma unroll
        for (int g = 0; g < 4; ++g)
          accP[g] = __builtin_amdgcn_mfma_f32_16x16x32_f16(af, bf[kt][g], accP[g], 0, 0, 0);
      }
#pragma unroll
      for (int reg = 0; reg < 4; ++reg) {
        int m = ((lane>>4)<<2) + reg;
        floatx4 pv = (floatx4){accP[0][reg], accP[1][reg], accP[2][reg], accP[3][reg]};
        *reinterpret_cast<floatx4*>(&preLDS[slot][(m*128 + en)*4]) = pv;
      }
    }

    floatx4 p4 = (floatx4){0.f, 0.f, 0.f, 0.f};
    if (lane < 32) {
      int mstep = ((t & 7) << 1) + rb;
      p4 = *reinterpret_cast<const floatx4*>(&preLDS[b & 1][(mstep*128 + en)*4]);
    }
    floatx4 acc[4];
#pragma unroll
    for (int g = 0; g < 4; ++g) acc[g] = (floatx4){p4[g], 0.f, 0.f, 0.f};

    const int cur = t & 1;
    if (arow) {
      a4 = hA[cur][0*8 + cIdx];
      a5 = hA[cur][1*8 + cIdx];
      a6 = hA[cur][2*8 + cIdx];
      a7 = hA[cur][3*8 + cIdx];
    }
#pragma unroll
    for (int g = 0; g < 4; ++g)
      acc[g] = __builtin_amdgcn_mfma_f32_16x16x32_f16(a4, bf[4][g], acc[g], 0, 0, 0);
#pragma unroll
    for (int g = 0; g < 4; ++g)
      acc[g] = __builtin_amdgcn_mfma_f32_16x16x32_f16(a5, bf[5][g], acc[g], 0, 0, 0);
#pragma unroll
    for (int g = 0; g < 4; ++g)
      acc[g] = __builtin_amdgcn_mfma_f32_16x16x32_f16(a6, bf[6][g], acc[g], 0, 0, 0);
#pragma unroll
    for (int g = 0; g < 4; ++g)
      acc[g] = __builtin_amdgcn_mfma_f32_16x16x32_f16(a7, bf[7][g], acc[g], 0, 0, 0);

    if (lane < 32) {
      float ii = fast_sigmoid(acc[0][0]);
      float ff = fast_sigmoid(acc[1][0]);
      float gg = fast_tanh(acc[2][0]);
      float oo = fast_sigmoid(acc[3][0]);
      cst = ff*cst + ii*gg;
      hl = oo*fast_tanh(cst);
      ((_Float16*)hA[cur^1])[eoff] = (_Float16)hl;
    }
  }

  // fused head: out[r] = sum_n h_last[r][n]*wlin[n] + blin
  if (lane < 32) head[rb*128 + en] = hl * wl;
  __syncthreads();
  if (tid < 2) {
    float s = blin[0];
    for (int n = 0; n < 128; ++n) s += head[tid*128 + n];
    out[r0 + tid] = s;
  }
}

extern "C" void kernel_launch(void* const* d_in, const int* in_sizes, int n_in,
                              void* d_out, int out_size, void* d_ws, size_t ws_size,
                              hipStream_t stream)
{
  const float* x    = (const float*)d_in[0];
  const float* wih0 = (const float*)d_in[1];
  const float* whh0 = (const float*)d_in[2];
  const float* bih0 = (const float*)d_in[3];
  const float* bhh0 = (const float*)d_in[4];
  const float* wih1 = (const float*)d_in[5];
  const float* whh1 = (const float*)d_in[6];
  const float* bih1 = (const float*)d_in[7];
  const float* bhh1 = (const float*)d_in[8];
  const float* wlin = (const float*)d_in[9];
  const float* blin = (const float*)d_in[10];
  float* out = (float*)d_out;

  char* ws = (char*)d_ws;
  _Float16* w0f = (_Float16*)(ws);               // 196608 B
  _Float16* w1f = (_Float16*)(ws + 196608);      // 262144 B
  float* bias0  = (float*)(ws + 458752);         // 2048 B
  float* bias1  = (float*)(ws + 460800);         // 2048 B
  _Float16* h1  = (_Float16*)(ws + 1048576);     // 64 MB inter-layer buffer

  prep_kernel<<<256, 256, 0, stream>>>(wih0, whh0, bih0, bhh0, wih1, whh1, bih1, bhh1,
                                       w0f, w1f, bias0, bias1);
  lstm_l0<<<256, 512, 0, stream>>>(x, w0f, bias0, h1);
  lstm_l1<<<256, 512, 0, stream>>>(h1, w1f, bias1, wlin, blin, out);
}